// Round 2
// baseline (1837.439 us; speedup 1.0000x reference)
//
#include <hip/hip_runtime.h>
#include <stdint.h>

typedef unsigned long long u64;
typedef uint32_t u32;
typedef uint16_t u16;

// Net: x (8192,6,32,48)
// L1: (6,32,48)->(12,15,23)   L2: (12,15,23)->(24,7,11)
// L3: (24,7,11)->(48,3,5)     L4: (48,3,5)->(96,1,2)
// Linear: 192 -> 360
#define NIMG 8192

// ---------------- workspace layout (bytes) ----------------
static const size_t O_TOT = 0;                                   // 512 u64 stats (zeroed by pack_k)
static const size_t O_X1  = 4096;                                // u16 [N][32][50]  ternary p|n<<8
static const size_t O_A2  = O_X1 + (size_t)NIMG*32*50*2;         // u16 [N][15][25]  12-bit
static const size_t O_A3  = O_A2 + (size_t)NIMG*15*25*2;         // u32 [N][7][13]   24-bit
static const size_t O_A4  = O_A3 + (size_t)NIMG*7*13*4;          // u64 [N][3][7]    48-bit
static const size_t O_AL  = O_A4 + (size_t)NIMG*3*7*8;           // u64 [N][3]       192-bit linear input
static const size_t O_W1  = O_AL + (size_t)NIMG*3*8;             // 120 u64
static const size_t O_W2  = O_W1 + 120*8;                        // 240 u64
static const size_t O_W3  = O_W2 + 240*8;                        // 960 u64
static const size_t O_W4  = O_W3 + 960*8;                        // 3840 u64
static const size_t O_WL  = O_W4 + 3840*8;                       // 2160 u64
static const size_t O_S   = O_WL + 2160*8;                       // reused S buffer (L1: s8-packed u32x3/pix = 34MB)

// ---------------- weight packing + stats zeroing ----------------
__global__ void pack_w_k(const float* w1, const float* w2, const float* w3,
                         const float* w4, const float* wl,
                         u64* W1, u64* W2, u64* W3, u64* W4, u64* WL, u64* tot) {
  if (blockIdx.x == 5) {              // zero the stats accumulators (ws is poisoned 0xAA)
    int t = threadIdx.x;
    tot[t] = 0; tot[t+256] = 0;
    return;
  }
  int u = blockIdx.x*256 + threadIdx.x;
  if (u < 60) {                       // L1: unit=(co*5+kh); 30-bit planes, ternary combined
    int co = u/5, kh = u%5;
    u64 wp=0, wn=0;
    for (int kw=0; kw<5; kw++) for (int ci=0; ci<6; ci++) {
      float v = w1[co*150 + ci*25 + kh*5 + kw];
      int pos = 6*kw + ci;
      if (v > 0.f) wp |= 1ull<<pos; else if (v < 0.f) wn |= 1ull<<pos;
    }
    W1[u*2]   = wp | (wn<<32);        // counts +1 products vs X = xp | xn<<32
    W1[u*2+1] = wn | (wp<<32);        // counts -1 products
  } else if (u < 180) {               // L2: 60-bit single plane
    int t = u-60; int co=t/5, kh=t%5;
    u64 wp=0, wn=0;
    for (int kw=0; kw<5; kw++) for (int ci=0; ci<12; ci++) {
      float v = w2[co*300 + ci*25 + kh*5 + kw];
      int pos = 12*kw+ci;
      if (v>0.f) wp |= 1ull<<pos; else if (v<0.f) wn |= 1ull<<pos;
    }
    W2[t*2] = wp; W2[t*2+1] = wn;
  } else if (u < 420) {               // L3: 120-bit, 2 words per plane
    int t = u-180; int co=t/5, kh=t%5;
    u64 wp[2]={0,0}, wn[2]={0,0};
    for (int kw=0; kw<5; kw++) for (int ci=0; ci<24; ci++) {
      float v = w3[co*600 + ci*25 + kh*5 + kw];
      int pos = 24*kw+ci;
      if (v>0.f) wp[pos>>6] |= 1ull<<(pos&63); else if (v<0.f) wn[pos>>6] |= 1ull<<(pos&63);
    }
    W3[t*4]=wp[0]; W3[t*4+1]=wp[1]; W3[t*4+2]=wn[0]; W3[t*4+3]=wn[1];
  } else if (u < 900) {               // L4: 240-bit, 4 words per plane
    int t = u-420; int co=t/5, kh=t%5;
    u64 wp[4]={0,0,0,0}, wn[4]={0,0,0,0};
    for (int kw=0; kw<5; kw++) for (int ci=0; ci<48; ci++) {
      float v = w4[co*1200 + ci*25 + kh*5 + kw];
      int pos = 48*kw+ci;
      if (v>0.f) wp[pos>>6] |= 1ull<<(pos&63); else if (v<0.f) wn[pos>>6] |= 1ull<<(pos&63);
    }
    for (int j=0;j<4;j++){ W4[t*8+j]=wp[j]; W4[t*8+4+j]=wn[j]; }
  } else if (u < 1260) {              // linear: 192-bit, 3 words per plane
    int o = u-900;
    u64 wp[3]={0,0,0}, wn[3]={0,0,0};
    for (int k=0;k<192;k++){
      float v = wl[o*192+k];
      if (v>0.f) wp[k>>6] |= 1ull<<(k&63); else if (v<0.f) wn[k>>6] |= 1ull<<(k&63);
    }
    for (int j=0;j<3;j++){ WL[o*6+j]=wp[j]; WL[o*6+3+j]=wn[j]; }
  }
}

// ---------------- binarize x (ternary) ----------------
__global__ __launch_bounds__(256) void binx_k(const float* __restrict__ x, u16* __restrict__ X1) {
  int gid = blockIdx.x*256+threadIdx.x;
  if (gid >= NIMG*32*48) return;
  int n = gid / 1536, r = gid % 1536, h = r/48, w = r%48;
  const float* xp = x + (size_t)n*9216 + h*48 + w;
  u32 v = 0;
  #pragma unroll
  for (int c=0;c<6;c++){ float t = xp[c*1536];
    v |= (t>0.f ? 1u:0u)<<c; v |= (t<0.f ? 1u:0u)<<(8+c); }
  u16* row = X1 + (size_t)n*1600 + h*50;
  row[w+1] = (u16)v;
  if (w==0)  row[0]  = 0;   // left pad
  if (w==47) row[49] = 0;   // right pad
}

// ---------------- conv layers (popcount) with fused exact stats ----------------
// conv1: S packed as 12 x s8 -> 3 u32 per pixel (|S| <= 150)
__global__ __launch_bounds__(256) void conv1_k(const u16* __restrict__ X1, const u64* __restrict__ W1,
                                               u32* __restrict__ S1, u64* __restrict__ tot) {
  __shared__ int ls[12], lq[12];
  int tid = threadIdx.x;
  if (tid < 12){ ls[tid]=0; lq[tid]=0; }
  __syncthreads();
  int pix = blockIdx.x*256+tid;
  if (pix < NIMG*345) {
    int n = pix/345, r = pix%345, oh = r/23, ow = r%23;
    int S[12];
    #pragma unroll
    for (int i=0;i<12;i++) S[i]=0;
    const u16* base = X1 + (size_t)n*1600;
    for (int kh=0; kh<5; kh++){
      int row = 2*oh-1+kh;
      if ((unsigned)row >= 32u) continue;
      const u16* p = base + row*50 + 2*ow;
      u64 xp=0, xn=0;
      #pragma unroll
      for (int i=0;i<5;i++){ u32 v = p[i];
        xp |= (u64)(v & 63u) << (6*i);
        xn |= (u64)(v >> 8)  << (6*i); }
      u64 X = xp | (xn<<32);
      const u64* wr = W1 + kh*2;
      #pragma unroll
      for (int co=0;co<12;co++)
        S[co] += __popcll(X & wr[co*10]) - __popcll(X & wr[co*10+1]);
    }
    u32* o = S1 + (size_t)pix*3;
    #pragma unroll
    for (int j=0;j<3;j++)
      o[j] = (u32)(S[4*j]&255) | ((u32)(S[4*j+1]&255)<<8) |
             ((u32)(S[4*j+2]&255)<<16) | ((u32)(S[4*j+3]&255)<<24);
    #pragma unroll
    for (int c=0;c<12;c++){ atomicAdd(&ls[c], S[c]); atomicAdd(&lq[c], S[c]*S[c]); }
  }
  __syncthreads();
  if (tid < 12){ atomicAdd(&tot[tid*2], (u64)(long long)ls[tid]);
                 atomicAdd(&tot[tid*2+1], (u64)(long long)lq[tid]); }
}

__global__ __launch_bounds__(256) void conv2_k(const u16* __restrict__ A2, const u64* __restrict__ W2,
                                               short* __restrict__ S2, u64* __restrict__ tot) {
  __shared__ int ls[24], lq[24];
  int tid = threadIdx.x;
  if (tid < 24){ ls[tid]=0; lq[tid]=0; }
  __syncthreads();
  int pix = blockIdx.x*256+tid;   // grid exact: 2464*256 == NIMG*77
  {
    int n = pix/77, r = pix%77, oh = r/11, ow = r%11;
    int S[24];
    #pragma unroll
    for (int i=0;i<24;i++) S[i]=0;
    const u16* base = A2 + (size_t)n*375;
    for (int kh=0; kh<5; kh++){
      int row = 2*oh-1+kh;
      if ((unsigned)row >= 15u) continue;
      const u16* p = base + row*25 + 2*ow;
      u64 X=0;
      #pragma unroll
      for (int i=0;i<5;i++) X |= (u64)p[i] << (12*i);
      const u64* wr = W2 + kh*2;
      #pragma unroll
      for (int co=0;co<24;co++)
        S[co] += __popcll(X & wr[co*10]) - __popcll(X & wr[co*10+1]);
    }
    short* o = S2 + (size_t)pix*24;
    #pragma unroll
    for (int co=0;co<24;co++) o[co] = (short)S[co];
    #pragma unroll
    for (int c=0;c<24;c++){ atomicAdd(&ls[c], S[c]); atomicAdd(&lq[c], S[c]*S[c]); }
  }
  __syncthreads();
  if (tid < 24){ atomicAdd(&tot[tid*2], (u64)(long long)ls[tid]);
                 atomicAdd(&tot[tid*2+1], (u64)(long long)lq[tid]); }
}

__global__ __launch_bounds__(256) void conv3_k(const u32* __restrict__ A3, const u64* __restrict__ W3,
                                               short* __restrict__ S3, u64* __restrict__ tot) {
  __shared__ int ls[48], lq[48];
  int tid = threadIdx.x;
  if (tid < 48){ ls[tid]=0; lq[tid]=0; }
  __syncthreads();
  int pix = blockIdx.x*256+tid;   // grid exact: 480*256 == NIMG*15
  {
    int n = pix/15, r = pix%15, oh = r/5, ow = r%5;
    int S[48];
    #pragma unroll
    for (int i=0;i<48;i++) S[i]=0;
    const u32* base = A3 + (size_t)n*91;
    for (int kh=0; kh<5; kh++){
      int row = 2*oh-1+kh;
      if ((unsigned)row >= 7u) continue;
      const u32* p = base + row*13 + 2*ow;
      u64 a0=p[0],a1=p[1],a2=p[2],a3=p[3],a4=p[4];
      u64 x0 = a0 | (a1<<24) | (a2<<48);
      u64 x1 = (a2>>16) | (a3<<8) | (a4<<32);
      const u64* wr = W3 + kh*4;
      #pragma unroll
      for (int co=0;co<48;co++){
        const u64* q = wr + co*20;
        S[co] += __popcll(x0 & q[0]) + __popcll(x1 & q[1])
               - __popcll(x0 & q[2]) - __popcll(x1 & q[3]);
      }
    }
    short* o = S3 + (size_t)pix*48;
    #pragma unroll
    for (int co=0;co<48;co++) o[co] = (short)S[co];
    #pragma unroll
    for (int c=0;c<48;c++){ atomicAdd(&ls[c], S[c]); atomicAdd(&lq[c], S[c]*S[c]); }
  }
  __syncthreads();
  if (tid < 48){ atomicAdd(&tot[tid*2], (u64)(long long)ls[tid]);
                 atomicAdd(&tot[tid*2+1], (u64)(long long)lq[tid]); }
}

__global__ __launch_bounds__(256) void conv4_k(const u64* __restrict__ A4, const u64* __restrict__ W4,
                                               short* __restrict__ S4, u64* __restrict__ tot) {
  __shared__ int ls[96], lq[96];
  int tid = threadIdx.x;
  if (tid < 96){ ls[tid]=0; lq[tid]=0; }
  __syncthreads();
  int gid = blockIdx.x*256+tid;   // grid exact: 256*256 == NIMG*2*4
  {
    int pix = gid>>2, grp = gid&3;     // 4 groups of 24 output channels
    int n = pix>>1, ow = pix&1;
    int S[24];
    #pragma unroll
    for (int i=0;i<24;i++) S[i]=0;
    const u64* base = A4 + (size_t)n*21;
    for (int kh=0; kh<5; kh++){
      int row = kh-1;                  // oh = 0 only
      if ((unsigned)row >= 3u) continue;
      const u64* p = base + row*7 + 2*ow;
      u64 a0=p[0],a1=p[1],a2=p[2],a3=p[3],a4=p[4];
      u64 x0 = a0 | (a1<<48);
      u64 x1 = (a1>>16) | (a2<<32);
      u64 x2 = (a2>>32) | (a3<<16);
      u64 x3 = a4;
      const u64* wr = W4 + kh*8;
      #pragma unroll
      for (int j=0;j<24;j++){
        const u64* q = wr + (grp*24+j)*40;
        S[j] += __popcll(x0&q[0]) + __popcll(x1&q[1]) + __popcll(x2&q[2]) + __popcll(x3&q[3])
              - __popcll(x0&q[4]) - __popcll(x1&q[5]) - __popcll(x2&q[6]) - __popcll(x3&q[7]);
      }
    }
    short* o = S4 + (size_t)pix*96 + grp*24;
    #pragma unroll
    for (int j=0;j<24;j++) o[j] = (short)S[j];
    #pragma unroll
    for (int j=0;j<24;j++){ int c = grp*24+j;
      atomicAdd(&ls[c], S[j]); atomicAdd(&lq[c], S[j]*S[j]); }
  }
  __syncthreads();
  if (tid < 96){ atomicAdd(&tot[tid*2], (u64)(long long)ls[tid]);
                 atomicAdd(&tot[tid*2+1], (u64)(long long)lq[tid]); }
}

// ---------------- BN threshold + bit-pack ----------------
template<int C>
__device__ void bn_params(const u64* tot, const float* g, const float* be, double cnt,
                          float* s_mu, float* s_k, float* s_be) {
  int t = threadIdx.x;
  if (t < C) {
    long long sum = (long long)tot[t*2];
    long long sq  = (long long)tot[t*2+1];
    double mu  = (double)sum / cnt;
    double var = (double)sq / cnt - mu*mu;
    double kk  = (double)g[t] / sqrt(var + 1e-5);
    s_mu[t] = (float)mu; s_k[t] = (float)kk; s_be[t] = be[t];
  }
  __syncthreads();
}

__global__ __launch_bounds__(256) void thresh1_k(const u32* __restrict__ S1, const u64* tot,
                                                 const float* g, const float* be, u16* __restrict__ A2){
  __shared__ float mu[12], kk[12], bb[12];
  bn_params<12>(tot, g, be, 2826240.0, mu, kk, bb);
  int pix = blockIdx.x*256+threadIdx.x;
  if (pix >= NIMG*345) return;
  int n=pix/345, r=pix%345, oh=r/23, ow=r%23;
  const u32* s = S1 + (size_t)pix*3;
  u32 w0=s[0], w1=s[1], w2=s[2];
  u32 wv=0;
  #pragma unroll
  for (int c=0;c<12;c++){
    u32 w = (c<4) ? w0 : (c<8) ? w1 : w2;
    int sv = (int)(w << ((3-(c&3))*8)) >> 24;   // sign-extend s8
    float v = ((float)sv-mu[c])*kk[c]+bb[c];
    wv |= (v>0.f?1u:0u)<<c;
  }
  u16* row = A2 + (size_t)n*375 + oh*25;
  row[ow+1] = (u16)wv;
  if (ow==0)  row[0]  = 0;
  if (ow==22) row[24] = 0;
}

__global__ __launch_bounds__(256) void thresh2_k(const short* __restrict__ S2, const u64* tot,
                                                 const float* g, const float* be, u32* __restrict__ A3){
  __shared__ float mu[24], kk[24], bb[24];
  bn_params<24>(tot, g, be, 630784.0, mu, kk, bb);
  int pix = blockIdx.x*256+threadIdx.x;
  if (pix >= NIMG*77) return;
  int n=pix/77, r=pix%77, oh=r/11, ow=r%11;
  const short* s = S2 + (size_t)pix*24;
  u32 wv=0;
  #pragma unroll
  for (int c=0;c<24;c++){ float v = ((float)s[c]-mu[c])*kk[c]+bb[c]; wv |= (v>0.f?1u:0u)<<c; }
  u32* row = A3 + (size_t)n*91 + oh*13;
  row[ow+1] = wv;
  if (ow==0)  row[0]  = 0;
  if (ow==10) row[12] = 0;
}

__global__ __launch_bounds__(256) void thresh3_k(const short* __restrict__ S3, const u64* tot,
                                                 const float* g, const float* be, u64* __restrict__ A4){
  __shared__ float mu[48], kk[48], bb[48];
  bn_params<48>(tot, g, be, 122880.0, mu, kk, bb);
  int pix = blockIdx.x*256+threadIdx.x;
  if (pix >= NIMG*15) return;
  int n=pix/15, r=pix%15, oh=r/5, ow=r%5;
  const short* s = S3 + (size_t)pix*48;
  u64 wv=0;
  #pragma unroll
  for (int c=0;c<48;c++){ float v = ((float)s[c]-mu[c])*kk[c]+bb[c]; wv |= (u64)(v>0.f?1u:0u)<<c; }
  u64* row = A4 + (size_t)n*21 + oh*7;
  row[ow+1] = wv;
  if (ow==0) row[0] = 0;
  if (ow==4) row[6] = 0;
}

__global__ __launch_bounds__(256) void thresh4_k(const short* __restrict__ S4, const u64* tot,
                                                 const float* g, const float* be, u64* __restrict__ aL){
  __shared__ float mu[96], kk[96], bb[96];
  bn_params<96>(tot, g, be, 16384.0, mu, kk, bb);
  int n = blockIdx.x*256+threadIdx.x;
  if (n >= NIMG) return;
  u64 a[3]={0,0,0};
  for (int w=0;w<2;w++){
    const short* s = S4 + ((size_t)n*2+w)*96;
    #pragma unroll
    for (int c=0;c<96;c++){
      float v = ((float)s[c]-mu[c])*kk[c]+bb[c];
      int k = c*2+w;                  // reshape(96,1,2)->192 ordering
      if (v>0.f) a[k>>6] |= 1ull<<(k&63);
    }
  }
  aL[(size_t)n*3]=a[0]; aL[(size_t)n*3+1]=a[1]; aL[(size_t)n*3+2]=a[2];
}

// ---------------- binarized linear ----------------
__global__ __launch_bounds__(256) void linear_k(const u64* __restrict__ aL, const u64* __restrict__ WL,
                                                const float* __restrict__ bl, float* __restrict__ out){
  int gid = blockIdx.x*256+threadIdx.x;
  if (gid >= NIMG*360) return;
  int o = gid%360, n = gid/360;
  const u64* a = aL + (size_t)n*3;
  const u64* w = WL + (size_t)o*6;
  int S = __popcll(a[0]&w[0]) + __popcll(a[1]&w[1]) + __popcll(a[2]&w[2])
        - __popcll(a[0]&w[3]) - __popcll(a[1]&w[4]) - __popcll(a[2]&w[5]);
  out[gid] = (float)S + bl[o];
}

extern "C" void kernel_launch(void* const* d_in, const int* in_sizes, int n_in,
                              void* d_out, int out_size, void* d_ws, size_t ws_size,
                              hipStream_t stream) {
  const float* x  = (const float*)d_in[0];
  const float* w1 = (const float*)d_in[1];
  const float* g1 = (const float*)d_in[3];
  const float* be1= (const float*)d_in[4];
  const float* w2 = (const float*)d_in[5];
  const float* g2 = (const float*)d_in[7];
  const float* be2= (const float*)d_in[8];
  const float* w3 = (const float*)d_in[9];
  const float* g3 = (const float*)d_in[11];
  const float* be3= (const float*)d_in[12];
  const float* w4 = (const float*)d_in[13];
  const float* g4 = (const float*)d_in[15];
  const float* be4= (const float*)d_in[16];
  const float* wl = (const float*)d_in[17];
  const float* bl = (const float*)d_in[18];

  char* ws = (char*)d_ws;
  u64* tot = (u64*)(ws + O_TOT);
  u16* X1  = (u16*)(ws + O_X1);
  u16* A2  = (u16*)(ws + O_A2);
  u32* A3  = (u32*)(ws + O_A3);
  u64* A4  = (u64*)(ws + O_A4);
  u64* aL  = (u64*)(ws + O_AL);
  u64* W1  = (u64*)(ws + O_W1);
  u64* W2  = (u64*)(ws + O_W2);
  u64* W3  = (u64*)(ws + O_W3);
  u64* W4  = (u64*)(ws + O_W4);
  u64* WL  = (u64*)(ws + O_WL);
  u32*   S1b = (u32*)(ws + O_S);
  short* Sb  = (short*)(ws + O_S);

  pack_w_k<<<6,256,0,stream>>>(w1,w2,w3,w4,wl, W1,W2,W3,W4,WL, tot);
  binx_k<<<49152,256,0,stream>>>(x, X1);

  conv1_k<<<11040,256,0,stream>>>(X1, W1, S1b, tot+0);
  thresh1_k<<<11040,256,0,stream>>>(S1b, tot+0, g1, be1, A2);

  conv2_k<<<2464,256,0,stream>>>(A2, W2, Sb, tot+24);
  thresh2_k<<<2464,256,0,stream>>>(Sb, tot+24, g2, be2, A3);

  conv3_k<<<480,256,0,stream>>>(A3, W3, Sb, tot+72);
  thresh3_k<<<480,256,0,stream>>>(Sb, tot+72, g3, be3, A4);

  conv4_k<<<256,256,0,stream>>>(A4, W4, Sb, tot+168);
  thresh4_k<<<32,256,0,stream>>>(Sb, tot+168, g4, be4, aL);

  linear_k<<<11520,256,0,stream>>>(aL, WL, bl, (float*)d_out);
}

// Round 3
// 866.213 us; speedup vs baseline: 2.1212x; 2.1212x over previous
//
#include <hip/hip_runtime.h>
#include <stdint.h>

typedef unsigned long long u64;
typedef uint32_t u32;
typedef uint16_t u16;

// Net: x (8192,6,32,48)
// L1: (6,32,48)->(12,15,23)   L2: (12,15,23)->(24,7,11)
// L3: (24,7,11)->(48,3,5)     L4: (48,3,5)->(96,1,2)
// Linear: 192 -> 360
#define NIMG 8192

// ---------------- workspace layout (bytes) ----------------
static const size_t O_TOT = 0;                                   // 512 u64 stats (zeroed by pack_k)
static const size_t O_X1  = 4096;                                // u16 [N][32][50]  ternary p|n<<8
static const size_t O_A2  = O_X1 + (size_t)NIMG*32*50*2;         // u16 [N][15][25]  12-bit
static const size_t O_A3  = O_A2 + (size_t)NIMG*15*25*2;         // u32 [N][7][13]   24-bit
static const size_t O_A4  = O_A3 + (size_t)NIMG*7*13*4;          // u64 [N][3][7]    48-bit
static const size_t O_AL  = O_A4 + (size_t)NIMG*3*7*8;           // u64 [N][3]       192-bit linear input
static const size_t O_W1  = O_AL + (size_t)NIMG*3*8;             // 120 u64
static const size_t O_W2  = O_W1 + 120*8;                        // 240 u64
static const size_t O_W3  = O_W2 + 240*8;                        // 960 u64
static const size_t O_W4  = O_W3 + 960*8;                        // 3840 u64
static const size_t O_WL  = O_W4 + 3840*8;                       // 2160 u64
static const size_t O_S   = O_WL + 2160*8;                       // reused S buffer (16B-aligned; L1 s8 u32x3 = 34MB)

// ---------------- weight packing + stats zeroing ----------------
__global__ void pack_w_k(const float* w1, const float* w2, const float* w3,
                         const float* w4, const float* wl,
                         u64* W1, u64* W2, u64* W3, u64* W4, u64* WL, u64* tot) {
  if (blockIdx.x == 5) {              // zero the stats accumulators (ws is poisoned 0xAA)
    int t = threadIdx.x;
    tot[t] = 0; tot[t+256] = 0;
    return;
  }
  int u = blockIdx.x*256 + threadIdx.x;
  if (u < 60) {                       // L1: unit=(co*5+kh); 30-bit planes, ternary combined
    int co = u/5, kh = u%5;
    u64 wp=0, wn=0;
    for (int kw=0; kw<5; kw++) for (int ci=0; ci<6; ci++) {
      float v = w1[co*150 + ci*25 + kh*5 + kw];
      int pos = 6*kw + ci;
      if (v > 0.f) wp |= 1ull<<pos; else if (v < 0.f) wn |= 1ull<<pos;
    }
    W1[u*2]   = wp | (wn<<32);        // counts +1 products vs X = xp | xn<<32
    W1[u*2+1] = wn | (wp<<32);        // counts -1 products
  } else if (u < 180) {               // L2: 60-bit single plane
    int t = u-60; int co=t/5, kh=t%5;
    u64 wp=0, wn=0;
    for (int kw=0; kw<5; kw++) for (int ci=0; ci<12; ci++) {
      float v = w2[co*300 + ci*25 + kh*5 + kw];
      int pos = 12*kw+ci;
      if (v>0.f) wp |= 1ull<<pos; else if (v<0.f) wn |= 1ull<<pos;
    }
    W2[t*2] = wp; W2[t*2+1] = wn;
  } else if (u < 420) {               // L3: 120-bit, 2 words per plane
    int t = u-180; int co=t/5, kh=t%5;
    u64 wp[2]={0,0}, wn[2]={0,0};
    for (int kw=0; kw<5; kw++) for (int ci=0; ci<24; ci++) {
      float v = w3[co*600 + ci*25 + kh*5 + kw];
      int pos = 24*kw+ci;
      if (v>0.f) wp[pos>>6] |= 1ull<<(pos&63); else if (v<0.f) wn[pos>>6] |= 1ull<<(pos&63);
    }
    W3[t*4]=wp[0]; W3[t*4+1]=wp[1]; W3[t*4+2]=wn[0]; W3[t*4+3]=wn[1];
  } else if (u < 900) {               // L4: 240-bit, 4 words per plane
    int t = u-420; int co=t/5, kh=t%5;
    u64 wp[4]={0,0,0,0}, wn[4]={0,0,0,0};
    for (int kw=0; kw<5; kw++) for (int ci=0; ci<48; ci++) {
      float v = w4[co*1200 + ci*25 + kh*5 + kw];
      int pos = 48*kw+ci;
      if (v>0.f) wp[pos>>6] |= 1ull<<(pos&63); else if (v<0.f) wn[pos>>6] |= 1ull<<(pos&63);
    }
    for (int j=0;j<4;j++){ W4[t*8+j]=wp[j]; W4[t*8+4+j]=wn[j]; }
  } else if (u < 1260) {              // linear: 192-bit, 3 words per plane
    int o = u-900;
    u64 wp[3]={0,0,0}, wn[3]={0,0,0};
    for (int k=0;k<192;k++){
      float v = wl[o*192+k];
      if (v>0.f) wp[k>>6] |= 1ull<<(k&63); else if (v<0.f) wn[k>>6] |= 1ull<<(k&63);
    }
    for (int j=0;j<3;j++){ WL[o*6+j]=wp[j]; WL[o*6+3+j]=wn[j]; }
  }
}

// ---------------- binarize x (ternary) ----------------
__global__ __launch_bounds__(256) void binx_k(const float* __restrict__ x, u16* __restrict__ X1) {
  int gid = blockIdx.x*256+threadIdx.x;   // grid exact: NIMG*32*48
  int n = gid / 1536, r = gid % 1536, h = r/48, w = r%48;
  const float* xp = x + (size_t)n*9216 + h*48 + w;
  u32 v = 0;
  #pragma unroll
  for (int c=0;c<6;c++){ float t = xp[c*1536];
    v |= (t>0.f ? 1u:0u)<<c; v |= (t<0.f ? 1u:0u)<<(8+c); }
  u16* row = X1 + (size_t)n*1600 + h*50;
  row[w+1] = (u16)v;
  if (w==0)  row[0]  = 0;   // left pad
  if (w==47) row[49] = 0;   // right pad
}

// ---------------- conv layers (popcount, NO fused stats) ----------------
// conv1: S packed as 12 x s8 -> 3 u32 per pixel (|S| <= 150)
__global__ __launch_bounds__(256) void conv1_k(const u16* __restrict__ X1, const u64* __restrict__ W1,
                                               u32* __restrict__ S1) {
  int pix = blockIdx.x*256+threadIdx.x;   // grid exact: NIMG*345
  int n = pix/345, r = pix%345, oh = r/23, ow = r%23;
  int S[12];
  #pragma unroll
  for (int i=0;i<12;i++) S[i]=0;
  const u16* base = X1 + (size_t)n*1600;
  for (int kh=0; kh<5; kh++){
    int row = 2*oh-1+kh;
    if ((unsigned)row >= 32u) continue;
    const u16* p = base + row*50 + 2*ow;
    u64 xp=0, xn=0;
    #pragma unroll
    for (int i=0;i<5;i++){ u32 v = p[i];
      xp |= (u64)(v & 63u) << (6*i);
      xn |= (u64)(v >> 8)  << (6*i); }
    u64 X = xp | (xn<<32);
    const u64* wr = W1 + kh*2;
    #pragma unroll
    for (int co=0;co<12;co++)
      S[co] += __popcll(X & wr[co*10]) - __popcll(X & wr[co*10+1]);
  }
  u32* o = S1 + (size_t)pix*3;
  #pragma unroll
  for (int j=0;j<3;j++)
    o[j] = (u32)(S[4*j]&255) | ((u32)(S[4*j+1]&255)<<8) |
           ((u32)(S[4*j+2]&255)<<16) | ((u32)(S[4*j+3]&255)<<24);
}

__global__ __launch_bounds__(256) void conv2_k(const u16* __restrict__ A2, const u64* __restrict__ W2,
                                               short* __restrict__ S2) {
  int pix = blockIdx.x*256+threadIdx.x;   // grid exact: NIMG*77
  int n = pix/77, r = pix%77, oh = r/11, ow = r%11;
  int S[24];
  #pragma unroll
  for (int i=0;i<24;i++) S[i]=0;
  const u16* base = A2 + (size_t)n*375;
  for (int kh=0; kh<5; kh++){
    int row = 2*oh-1+kh;
    if ((unsigned)row >= 15u) continue;
    const u16* p = base + row*25 + 2*ow;
    u64 X=0;
    #pragma unroll
    for (int i=0;i<5;i++) X |= (u64)p[i] << (12*i);
    const u64* wr = W2 + kh*2;
    #pragma unroll
    for (int co=0;co<24;co++)
      S[co] += __popcll(X & wr[co*10]) - __popcll(X & wr[co*10+1]);
  }
  short* o = S2 + (size_t)pix*24;
  #pragma unroll
  for (int co=0;co<24;co++) o[co] = (short)S[co];
}

__global__ __launch_bounds__(256) void conv3_k(const u32* __restrict__ A3, const u64* __restrict__ W3,
                                               short* __restrict__ S3) {
  int pix = blockIdx.x*256+threadIdx.x;   // grid exact: NIMG*15
  int n = pix/15, r = pix%15, oh = r/5, ow = r%5;
  int S[48];
  #pragma unroll
  for (int i=0;i<48;i++) S[i]=0;
  const u32* base = A3 + (size_t)n*91;
  for (int kh=0; kh<5; kh++){
    int row = 2*oh-1+kh;
    if ((unsigned)row >= 7u) continue;
    const u32* p = base + row*13 + 2*ow;
    u64 a0=p[0],a1=p[1],a2=p[2],a3=p[3],a4=p[4];
    u64 x0 = a0 | (a1<<24) | (a2<<48);
    u64 x1 = (a2>>16) | (a3<<8) | (a4<<32);
    const u64* wr = W3 + kh*4;
    #pragma unroll
    for (int co=0;co<48;co++){
      const u64* q = wr + co*20;
      S[co] += __popcll(x0 & q[0]) + __popcll(x1 & q[1])
             - __popcll(x0 & q[2]) - __popcll(x1 & q[3]);
    }
  }
  short* o = S3 + (size_t)pix*48;
  #pragma unroll
  for (int co=0;co<48;co++) o[co] = (short)S[co];
}

__global__ __launch_bounds__(256) void conv4_k(const u64* __restrict__ A4, const u64* __restrict__ W4,
                                               short* __restrict__ S4) {
  int gid = blockIdx.x*256+threadIdx.x;   // grid exact: NIMG*2*4
  int pix = gid>>2, grp = gid&3;          // 4 groups of 24 output channels
  int n = pix>>1, ow = pix&1;
  int S[24];
  #pragma unroll
  for (int i=0;i<24;i++) S[i]=0;
  const u64* base = A4 + (size_t)n*21;
  for (int kh=0; kh<5; kh++){
    int row = kh-1;                       // oh = 0 only
    if ((unsigned)row >= 3u) continue;
    const u64* p = base + row*7 + 2*ow;
    u64 a0=p[0],a1=p[1],a2=p[2],a3=p[3],a4=p[4];
    u64 x0 = a0 | (a1<<48);
    u64 x1 = (a1>>16) | (a2<<32);
    u64 x2 = (a2>>32) | (a3<<16);
    u64 x3 = a4;
    const u64* wr = W4 + kh*8;
    #pragma unroll
    for (int j=0;j<24;j++){
      const u64* q = wr + (grp*24+j)*40;
      S[j] += __popcll(x0&q[0]) + __popcll(x1&q[1]) + __popcll(x2&q[2]) + __popcll(x3&q[3])
            - __popcll(x0&q[4]) - __popcll(x1&q[5]) - __popcll(x2&q[6]) - __popcll(x3&q[7]);
    }
  }
  short* o = S4 + (size_t)pix*96 + grp*24;
  #pragma unroll
  for (int j=0;j<24;j++) o[j] = (short)S[j];
}

// ---------------- non-atomic LDS tree block reduction ----------------
// rows <= 24; lds is int[24*265]; 265 stride: pad breaks bank alignment, cols 256..263 hold
// per-segment partials. Returns the block total for row==threadIdx.x (threadIdx.x < NR).
#define LSTR 265
template<int NR>
__device__ long long tree_reduce(const int (&vals)[NR], int* lds){
  int t = threadIdx.x;
  #pragma unroll
  for (int r=0;r<NR;r++) lds[r*LSTR + t] = vals[r];
  __syncthreads();
  if (t < NR*8) {
    int r = t % NR, seg = t / NR;         // 8 segments of 32
    const int* row = lds + r*LSTR + seg*32;
    int s = 0;
    #pragma unroll
    for (int i=0;i<32;i++) s += row[i];
    lds[r*LSTR + 256 + seg] = s;
  }
  __syncthreads();
  long long res = 0;
  if (t < NR) {
    const int* row = lds + t*LSTR + 256;
    int s = 0;
    #pragma unroll
    for (int i=0;i<8;i++) s += row[i];
    res = s;
  }
  __syncthreads();                        // safe LDS reuse by next phase
  return res;
}

// ---------------- per-channel stats (exact integer, register acc + tree) ----------------
// L1: s8-packed u32 x3 per pixel, C=12. Sum and sq reduced in one 24-row phase.
__global__ __launch_bounds__(256) void stats1_k(const u32* __restrict__ S1, u64* __restrict__ tot){
  __shared__ int lds[24*LSTR];
  int acc[12], q[12];
  #pragma unroll
  for (int i=0;i<12;i++){ acc[i]=0; q[i]=0; }
  int nt = gridDim.x*256;
  for (int p = blockIdx.x*256+threadIdx.x; p < NIMG*345; p += nt){
    u32 w0=S1[(size_t)p*3], w1=S1[(size_t)p*3+1], w2=S1[(size_t)p*3+2];
    #pragma unroll
    for (int c=0;c<12;c++){
      u32 w = (c<4)?w0:(c<8)?w1:w2;
      int v = (int)(w << ((3-(c&3))*8)) >> 24;
      acc[c]+=v; q[c]+=v*v;
    }
  }
  int vals[24];
  #pragma unroll
  for (int c=0;c<12;c++){ vals[c]=acc[c]; vals[12+c]=q[c]; }
  long long rs = tree_reduce<24>(vals, lds);
  int t = threadIdx.x;
  if (t < 12)       atomicAdd(&tot[t*2],        (u64)rs);
  else if (t < 24)  atomicAdd(&tot[(t-12)*2+1], (u64)rs);
}

// L2: C=24 shorts per pixel, loop over pixels; two phases (sum, sq).
__global__ __launch_bounds__(256) void stats2_k(const short* __restrict__ S, u64* __restrict__ tot){
  __shared__ int lds[24*LSTR];
  int acc[24], q[24];
  #pragma unroll
  for (int i=0;i<24;i++){ acc[i]=0; q[i]=0; }
  int nt = gridDim.x*256;
  for (int p = blockIdx.x*256+threadIdx.x; p < NIMG*77; p += nt){
    const int4* s4 = (const int4*)(S + (size_t)p*24);
    int4 A=s4[0], B=s4[1], Cc=s4[2];
    int w[12]={A.x,A.y,A.z,A.w,B.x,B.y,B.z,B.w,Cc.x,Cc.y,Cc.z,Cc.w};
    #pragma unroll
    for (int j=0;j<12;j++){
      int v0=(int)(short)(w[j]&0xffff), v1=w[j]>>16;
      acc[2*j]+=v0; q[2*j]+=v0*v0; acc[2*j+1]+=v1; q[2*j+1]+=v1*v1;
    }
  }
  long long rs = tree_reduce<24>(acc, lds);
  int t = threadIdx.x;
  if (t < 24) atomicAdd(&tot[t*2], (u64)rs);
  rs = tree_reduce<24>(q, lds);
  if (t < 24) atomicAdd(&tot[t*2+1], (u64)rs);
}

// L3/L4: one pixel per thread (grid exact = npix), C in {48,96}, chunks of 24 channels.
__global__ __launch_bounds__(256) void statsP_k(const short* __restrict__ S, u64* __restrict__ tot, int C){
  __shared__ int lds[24*LSTR];
  int pix = blockIdx.x*256+threadIdx.x;
  const short* s = S + (size_t)pix*C;
  int t = threadIdx.x;
  for (int c0=0; c0<C; c0+=24){
    const int4* s4 = (const int4*)(s + c0);
    int4 A=s4[0], B=s4[1], Cc=s4[2];
    int w[12]={A.x,A.y,A.z,A.w,B.x,B.y,B.z,B.w,Cc.x,Cc.y,Cc.z,Cc.w};
    int v[24];
    #pragma unroll
    for (int j=0;j<12;j++){ v[2*j]=(int)(short)(w[j]&0xffff); v[2*j+1]=w[j]>>16; }
    long long rs = tree_reduce<24>(v, lds);
    if (t < 24) atomicAdd(&tot[(c0+t)*2], (u64)rs);
    int vq[24];
    #pragma unroll
    for (int r=0;r<24;r++) vq[r]=v[r]*v[r];
    rs = tree_reduce<24>(vq, lds);
    if (t < 24) atomicAdd(&tot[(c0+t)*2+1], (u64)rs);
  }
}

// ---------------- BN threshold + bit-pack ----------------
template<int C>
__device__ void bn_params(const u64* tot, const float* g, const float* be, double cnt,
                          float* s_mu, float* s_k, float* s_be) {
  int t = threadIdx.x;
  if (t < C) {
    long long sum = (long long)tot[t*2];
    long long sq  = (long long)tot[t*2+1];
    double mu  = (double)sum / cnt;
    double var = (double)sq / cnt - mu*mu;
    double kk  = (double)g[t] / sqrt(var + 1e-5);
    s_mu[t] = (float)mu; s_k[t] = (float)kk; s_be[t] = be[t];
  }
  __syncthreads();
}

__global__ __launch_bounds__(256) void thresh1_k(const u32* __restrict__ S1, const u64* tot,
                                                 const float* g, const float* be, u16* __restrict__ A2){
  __shared__ float mu[12], kk[12], bb[12];
  bn_params<12>(tot, g, be, 2826240.0, mu, kk, bb);
  int pix = blockIdx.x*256+threadIdx.x;   // grid exact
  int n=pix/345, r=pix%345, oh=r/23, ow=r%23;
  const u32* s = S1 + (size_t)pix*3;
  u32 w0=s[0], w1=s[1], w2=s[2];
  u32 wv=0;
  #pragma unroll
  for (int c=0;c<12;c++){
    u32 w = (c<4) ? w0 : (c<8) ? w1 : w2;
    int sv = (int)(w << ((3-(c&3))*8)) >> 24;   // sign-extend s8
    float v = ((float)sv-mu[c])*kk[c]+bb[c];
    wv |= (v>0.f?1u:0u)<<c;
  }
  u16* row = A2 + (size_t)n*375 + oh*25;
  row[ow+1] = (u16)wv;
  if (ow==0)  row[0]  = 0;
  if (ow==22) row[24] = 0;
}

__global__ __launch_bounds__(256) void thresh2_k(const short* __restrict__ S2, const u64* tot,
                                                 const float* g, const float* be, u32* __restrict__ A3){
  __shared__ float mu[24], kk[24], bb[24];
  bn_params<24>(tot, g, be, 630784.0, mu, kk, bb);
  int pix = blockIdx.x*256+threadIdx.x;   // grid exact
  int n=pix/77, r=pix%77, oh=r/11, ow=r%11;
  const short* s = S2 + (size_t)pix*24;
  u32 wv=0;
  #pragma unroll
  for (int c=0;c<24;c++){ float v = ((float)s[c]-mu[c])*kk[c]+bb[c]; wv |= (v>0.f?1u:0u)<<c; }
  u32* row = A3 + (size_t)n*91 + oh*13;
  row[ow+1] = wv;
  if (ow==0)  row[0]  = 0;
  if (ow==10) row[12] = 0;
}

__global__ __launch_bounds__(256) void thresh3_k(const short* __restrict__ S3, const u64* tot,
                                                 const float* g, const float* be, u64* __restrict__ A4){
  __shared__ float mu[48], kk[48], bb[48];
  bn_params<48>(tot, g, be, 122880.0, mu, kk, bb);
  int pix = blockIdx.x*256+threadIdx.x;   // grid exact
  int n=pix/15, r=pix%15, oh=r/5, ow=r%5;
  const short* s = S3 + (size_t)pix*48;
  u64 wv=0;
  #pragma unroll
  for (int c=0;c<48;c++){ float v = ((float)s[c]-mu[c])*kk[c]+bb[c]; wv |= (u64)(v>0.f?1u:0u)<<c; }
  u64* row = A4 + (size_t)n*21 + oh*7;
  row[ow+1] = wv;
  if (ow==0) row[0] = 0;
  if (ow==4) row[6] = 0;
}

__global__ __launch_bounds__(256) void thresh4_k(const short* __restrict__ S4, const u64* tot,
                                                 const float* g, const float* be, u64* __restrict__ aL){
  __shared__ float mu[96], kk[96], bb[96];
  bn_params<96>(tot, g, be, 16384.0, mu, kk, bb);
  int n = blockIdx.x*256+threadIdx.x;
  if (n >= NIMG) return;
  u64 a[3]={0,0,0};
  for (int w=0;w<2;w++){
    const short* s = S4 + ((size_t)n*2+w)*96;
    #pragma unroll
    for (int c=0;c<96;c++){
      float v = ((float)s[c]-mu[c])*kk[c]+bb[c];
      int k = c*2+w;                  // reshape(96,1,2)->192 ordering
      if (v>0.f) a[k>>6] |= 1ull<<(k&63);
    }
  }
  aL[(size_t)n*3]=a[0]; aL[(size_t)n*3+1]=a[1]; aL[(size_t)n*3+2]=a[2];
}

// ---------------- binarized linear ----------------
__global__ __launch_bounds__(256) void linear_k(const u64* __restrict__ aL, const u64* __restrict__ WL,
                                                const float* __restrict__ bl, float* __restrict__ out){
  int gid = blockIdx.x*256+threadIdx.x;   // grid exact: NIMG*360
  int o = gid%360, n = gid/360;
  const u64* a = aL + (size_t)n*3;
  const u64* w = WL + (size_t)o*6;
  int S = __popcll(a[0]&w[0]) + __popcll(a[1]&w[1]) + __popcll(a[2]&w[2])
        - __popcll(a[0]&w[3]) - __popcll(a[1]&w[4]) - __popcll(a[2]&w[5]);
  out[gid] = (float)S + bl[o];
}

extern "C" void kernel_launch(void* const* d_in, const int* in_sizes, int n_in,
                              void* d_out, int out_size, void* d_ws, size_t ws_size,
                              hipStream_t stream) {
  const float* x  = (const float*)d_in[0];
  const float* w1 = (const float*)d_in[1];
  const float* g1 = (const float*)d_in[3];
  const float* be1= (const float*)d_in[4];
  const float* w2 = (const float*)d_in[5];
  const float* g2 = (const float*)d_in[7];
  const float* be2= (const float*)d_in[8];
  const float* w3 = (const float*)d_in[9];
  const float* g3 = (const float*)d_in[11];
  const float* be3= (const float*)d_in[12];
  const float* w4 = (const float*)d_in[13];
  const float* g4 = (const float*)d_in[15];
  const float* be4= (const float*)d_in[16];
  const float* wl = (const float*)d_in[17];
  const float* bl = (const float*)d_in[18];

  char* ws = (char*)d_ws;
  u64* tot = (u64*)(ws + O_TOT);
  u16* X1  = (u16*)(ws + O_X1);
  u16* A2  = (u16*)(ws + O_A2);
  u32* A3  = (u32*)(ws + O_A3);
  u64* A4  = (u64*)(ws + O_A4);
  u64* aL  = (u64*)(ws + O_AL);
  u64* W1  = (u64*)(ws + O_W1);
  u64* W2  = (u64*)(ws + O_W2);
  u64* W3  = (u64*)(ws + O_W3);
  u64* W4  = (u64*)(ws + O_W4);
  u64* WL  = (u64*)(ws + O_WL);
  u32*   S1b = (u32*)(ws + O_S);
  short* Sb  = (short*)(ws + O_S);

  pack_w_k<<<6,256,0,stream>>>(w1,w2,w3,w4,wl, W1,W2,W3,W4,WL, tot);
  binx_k<<<49152,256,0,stream>>>(x, X1);

  conv1_k<<<11040,256,0,stream>>>(X1, W1, S1b);
  stats1_k<<<1024,256,0,stream>>>(S1b, tot+0);
  thresh1_k<<<11040,256,0,stream>>>(S1b, tot+0, g1, be1, A2);

  conv2_k<<<2464,256,0,stream>>>(A2, W2, Sb);
  stats2_k<<<512,256,0,stream>>>(Sb, tot+24);
  thresh2_k<<<2464,256,0,stream>>>(Sb, tot+24, g2, be2, A3);

  conv3_k<<<480,256,0,stream>>>(A3, W3, Sb);
  statsP_k<<<480,256,0,stream>>>(Sb, tot+72, 48);
  thresh3_k<<<480,256,0,stream>>>(Sb, tot+72, g3, be3, A4);

  conv4_k<<<256,256,0,stream>>>(A4, W4, Sb);
  statsP_k<<<64,256,0,stream>>>(Sb, tot+168, 96);
  thresh4_k<<<32,256,0,stream>>>(Sb, tot+168, g4, be4, aL);

  linear_k<<<11520,256,0,stream>>>(aL, WL, bl, (float*)d_out);
}